// Round 1
// baseline (7819.587 us; speedup 1.0000x reference)
//
#include <hip/hip_runtime.h>
#include <hip/hip_bf16.h>
#include <cstdint>
#include <cstddef>

// Problem constants
#define Bn 64
#define Pn 196
#define ENCn 2048
#define DECn 512
#define ATTn 512
#define En 300
#define Vn 30000
#define Tn 21
#define STEPSn 20
#define Gn 2048  // 4*DEC gate width

// ---- workspace layout (float offsets) ----
#define WS_ENCPROJ ((size_t)0)
#define WS_WIHT  (WS_ENCPROJ + (size_t)Bn*Pn*ATTn)        // [2348][2048]
#define WS_WHHT  (WS_WIHT + (size_t)(En+ENCn)*Gn)         // [512][2048]
#define WS_MEANF (WS_WHHT + (size_t)DECn*Gn)              // [64][2048]
#define WS_H     (WS_MEANF + (size_t)Bn*ENCn)             // [64][512]
#define WS_C     (WS_H + (size_t)Bn*DECn)
#define WS_HDEC  (WS_C + (size_t)Bn*DECn)
#define WS_CTX   (WS_HDEC + (size_t)Bn*DECn)              // [64][2048]
#define WS_GATES (WS_CTX + (size_t)Bn*ENCn)               // [64][2048]
// total = 12,771,328 floats = 48.7 MiB

// ---- output layout (float offsets into d_out) ----
#define OUT_ALPHAS ((size_t)Bn*STEPSn*Vn)                 // 38,400,000
#define OUT_CAPT   (OUT_ALPHAS + (size_t)Bn*STEPSn*Pn)    // 38,650,880
#define OUT_SEQ    (OUT_CAPT + (size_t)Bn*Tn)             // 38,652,224

// ================= precompute kernels =================

// mean over P for each (b, e)
__global__ __launch_bounds__(256) void k_mean(const float* __restrict__ feat,
                                              float* __restrict__ mean_f) {
    int b = blockIdx.x;
    const float* fb = feat + (size_t)b * Pn * ENCn;
    for (int e = threadIdx.x; e < ENCn; e += 256) {
        float s = 0.f;
        #pragma unroll 4
        for (int p = 0; p < Pn; ++p) s += fb[(size_t)p * ENCn + e];
        mean_f[(size_t)b * ENCn + e] = s * (1.0f / (float)Pn);
    }
}

// h0/c0 = mean_f @ W_h0/W_c0 + b ;  grid (2, 16), 4 batches per thread
__global__ __launch_bounds__(256) void k_init_state(
        const float* __restrict__ mf,
        const float* __restrict__ Wh, const float* __restrict__ bh,
        const float* __restrict__ Wc, const float* __restrict__ bc,
        float* __restrict__ h, float* __restrict__ c) {
    int n = blockIdx.x * 256 + threadIdx.x;   // 0..511
    int b0 = blockIdx.y * 4;
    float ah[4], ac[4];
    float bhv = bh[n], bcv = bc[n];
    #pragma unroll
    for (int j = 0; j < 4; ++j) { ah[j] = bhv; ac[j] = bcv; }
    for (int k = 0; k < ENCn; ++k) {
        float wh = Wh[(size_t)k * DECn + n];
        float wc = Wc[(size_t)k * DECn + n];
        #pragma unroll
        for (int j = 0; j < 4; ++j) {
            float a = mf[(size_t)(b0 + j) * ENCn + k];
            ah[j] += a * wh;
            ac[j] += a * wc;
        }
    }
    #pragma unroll
    for (int j = 0; j < 4; ++j) {
        h[(size_t)(b0 + j) * DECn + n] = ah[j];
        c[(size_t)(b0 + j) * DECn + n] = ac[j];
    }
}

// generic transpose: in [R][C] -> out [C][R]
__global__ __launch_bounds__(256) void k_transpose(const float* __restrict__ in,
                                                   float* __restrict__ out,
                                                   int R, int C) {
    __shared__ float tile[32][33];
    int c0 = blockIdx.x * 32, r0 = blockIdx.y * 32;
    int tx = threadIdx.x & 31, ty = threadIdx.x >> 5;  // 32 x 8
    for (int i = ty; i < 32; i += 8) {
        int r = r0 + i, cc = c0 + tx;
        tile[i][tx] = (r < R && cc < C) ? in[(size_t)r * C + cc] : 0.f;
    }
    __syncthreads();
    for (int i = ty; i < 32; i += 8) {
        int cc = c0 + i, r = r0 + tx;
        if (cc < C && r < R) out[(size_t)cc * R + r] = tile[tx][i];
    }
}

// enc_proj = features(12544x2048) @ W_enc(2048x512) + b_enc ; 64x64 tiles
__global__ __launch_bounds__(256) void k_encproj(const float* __restrict__ A,
                                                 const float* __restrict__ Bm,
                                                 const float* __restrict__ bias,
                                                 float* __restrict__ Cm) {
    __shared__ float As[64][17];
    __shared__ float Bs[16][65];
    int row0 = blockIdx.x * 64, col0 = blockIdx.y * 64;
    int tid = threadIdx.x;
    int tx = tid & 15, ty = tid >> 4;
    float acc[4][4];
    #pragma unroll
    for (int i = 0; i < 4; ++i)
        #pragma unroll
        for (int j = 0; j < 4; ++j) acc[i][j] = 0.f;

    for (int k0 = 0; k0 < ENCn; k0 += 16) {
        {   // A tile 64x16
            int r = tid >> 2, kq = (tid & 3) * 4;
            float4 v = *(const float4*)&A[(size_t)(row0 + r) * ENCn + k0 + kq];
            As[r][kq] = v.x; As[r][kq + 1] = v.y; As[r][kq + 2] = v.z; As[r][kq + 3] = v.w;
        }
        {   // B tile 16x64
            int kk = tid >> 4, nq = (tid & 15) * 4;
            float4 v = *(const float4*)&Bm[(size_t)(k0 + kk) * ATTn + col0 + nq];
            Bs[kk][nq] = v.x; Bs[kk][nq + 1] = v.y; Bs[kk][nq + 2] = v.z; Bs[kk][nq + 3] = v.w;
        }
        __syncthreads();
        #pragma unroll
        for (int kk = 0; kk < 16; ++kk) {
            float a[4], bb[4];
            #pragma unroll
            for (int i = 0; i < 4; ++i) a[i] = As[ty * 4 + i][kk];
            #pragma unroll
            for (int j = 0; j < 4; ++j) bb[j] = Bs[kk][tx * 4 + j];
            #pragma unroll
            for (int i = 0; i < 4; ++i)
                #pragma unroll
                for (int j = 0; j < 4; ++j) acc[i][j] += a[i] * bb[j];
        }
        __syncthreads();
    }
    #pragma unroll
    for (int i = 0; i < 4; ++i) {
        int r = row0 + ty * 4 + i;
        #pragma unroll
        for (int j = 0; j < 4; ++j) {
            int cc = col0 + tx * 4 + j;
            Cm[(size_t)r * ATTn + cc] = acc[i][j] + bias[cc];
        }
    }
}

// small GEMM: C[64,N] = A[64,K] @ B[K,N] + bias ; grid (ceil(N/256), 16), 4 b/thread
__global__ __launch_bounds__(256) void k_small_gemm(const float* __restrict__ A, int K,
                                                    const float* __restrict__ Bm, int N,
                                                    const float* __restrict__ bias,
                                                    float* __restrict__ Cm) {
    int n = blockIdx.x * 256 + threadIdx.x;
    if (n >= N) return;
    int b0 = blockIdx.y * 4;
    float bv = bias[n];
    float acc[4];
    #pragma unroll
    for (int j = 0; j < 4; ++j) acc[j] = bv;
    for (int k = 0; k < K; ++k) {
        float w = Bm[(size_t)k * N + n];
        #pragma unroll
        for (int j = 0; j < 4; ++j) acc[j] += A[(size_t)(b0 + j) * K + k] * w;
    }
    #pragma unroll
    for (int j = 0; j < 4; ++j) Cm[(size_t)(b0 + j) * N + n] = acc[j];
}

// captions + seq_length passthrough (order is identity: caption_len constant)
__global__ __launch_bounds__(256) void k_tail(const int* __restrict__ captions,
                                              const int* __restrict__ caption_len,
                                              float* __restrict__ out) {
    int i = blockIdx.x * 256 + threadIdx.x;
    if (i < Bn * Tn) {
        out[OUT_CAPT + i] = (float)captions[i];
    } else if (i < Bn * Tn + Bn) {
        int b = i - Bn * Tn;
        out[OUT_SEQ + b] = (float)(caption_len[b] - 1);
    }
}

// ================= per-step kernels =================

// scores + softmax -> alphas(d_out). one block per b.
__global__ __launch_bounds__(256) void k_attn(const float* __restrict__ enc_proj,
                                              const float* __restrict__ hdec,
                                              const float* __restrict__ W_att,
                                              const float* __restrict__ b_att,
                                              float* __restrict__ alphas_out, int t) {
    __shared__ float hs[ATTn];
    __shared__ float wa[ATTn];
    __shared__ float sc[Pn];
    __shared__ float red[4];
    int b = blockIdx.x, tid = threadIdx.x;
    for (int i = tid; i < ATTn; i += 256) {
        hs[i] = hdec[(size_t)b * ATTn + i];
        wa[i] = W_att[i];
    }
    __syncthreads();
    int wave = tid >> 6, lane = tid & 63;
    float batt = b_att[0];
    for (int p = wave; p < Pn; p += 4) {
        const float* ep = enc_proj + ((size_t)b * Pn + p) * ATTn;
        float s = 0.f;
        #pragma unroll 2
        for (int a = lane; a < ATTn; a += 64) {
            float v = ep[a] + hs[a];
            v = fmaxf(v, 0.f);
            s += v * wa[a];
        }
        #pragma unroll
        for (int off = 32; off > 0; off >>= 1) s += __shfl_xor(s, off);
        if (lane == 0) sc[p] = s + batt;
    }
    __syncthreads();
    float v = (tid < Pn) ? sc[tid] : -1e30f;
    float m = v;
    #pragma unroll
    for (int off = 32; off > 0; off >>= 1) m = fmaxf(m, __shfl_xor(m, off));
    if (lane == 0) red[wave] = m;
    __syncthreads();
    float M = fmaxf(fmaxf(red[0], red[1]), fmaxf(red[2], red[3]));
    __syncthreads();
    float e = (tid < Pn) ? expf(v - M) : 0.f;
    float s = e;
    #pragma unroll
    for (int off = 32; off > 0; off >>= 1) s += __shfl_xor(s, off);
    if (lane == 0) red[wave] = s;
    __syncthreads();
    float S = red[0] + red[1] + red[2] + red[3];
    if (tid < Pn) {
        alphas_out[((size_t)b * STEPSn + t) * Pn + tid] = e / S;
    }
}

// ctx[b,:] = sum_p alpha[b,p] * features[b,p,:] ; grid (64, 8)
__global__ __launch_bounds__(256) void k_ctx(const float* __restrict__ feat,
                                             const float* __restrict__ alphas,
                                             float* __restrict__ ctx, int t) {
    __shared__ float al[Pn];
    int b = blockIdx.x, ec = blockIdx.y, tid = threadIdx.x;
    if (tid < Pn) al[tid] = alphas[((size_t)b * STEPSn + t) * Pn + tid];
    __syncthreads();
    int e = ec * 256 + tid;
    const float* fb = feat + (size_t)b * Pn * ENCn + e;
    float acc = 0.f;
    #pragma unroll 4
    for (int p = 0; p < Pn; ++p) acc += al[p] * fb[(size_t)p * ENCn];
    ctx[(size_t)b * ENCn + e] = acc;
}

// gates = emb_t @ WihT[0:300] + ctx @ WihT[300:2348] + h @ WhhT + b_ih + b_hh
// grid (8, 16): g tile 256, 4 b/thread
__global__ __launch_bounds__(256) void k_gates(const float* __restrict__ emb,
                                               const int* __restrict__ captions,
                                               const float* __restrict__ ctx,
                                               const float* __restrict__ h,
                                               const float* __restrict__ WihT,
                                               const float* __restrict__ WhhT,
                                               const float* __restrict__ b_ih,
                                               const float* __restrict__ b_hh,
                                               float* __restrict__ gates, int t) {
    int g = blockIdx.x * 256 + threadIdx.x;  // 0..2047
    int b0 = blockIdx.y * 4;
    float bias = b_ih[g] + b_hh[g];
    float acc[4];
    #pragma unroll
    for (int j = 0; j < 4; ++j) acc[j] = bias;

    const float* er[4];
    #pragma unroll
    for (int j = 0; j < 4; ++j)
        er[j] = emb + (size_t)captions[(b0 + j) * Tn + t] * En;
    for (int k = 0; k < En; ++k) {
        float w = WihT[(size_t)k * Gn + g];
        #pragma unroll
        for (int j = 0; j < 4; ++j) acc[j] += er[j][k] * w;
    }
    const float* WihT_ctx = WihT + (size_t)En * Gn;
    for (int k = 0; k < ENCn; ++k) {
        float w = WihT_ctx[(size_t)k * Gn + g];
        #pragma unroll
        for (int j = 0; j < 4; ++j) acc[j] += ctx[(size_t)(b0 + j) * ENCn + k] * w;
    }
    for (int k = 0; k < DECn; ++k) {
        float w = WhhT[(size_t)k * Gn + g];
        #pragma unroll
        for (int j = 0; j < 4; ++j) acc[j] += h[(size_t)(b0 + j) * DECn + k] * w;
    }
    #pragma unroll
    for (int j = 0; j < 4; ++j) gates[(size_t)(b0 + j) * Gn + g] = acc[j];
}

// LSTM pointwise: h,c updated in place. grid 128
__global__ __launch_bounds__(256) void k_lstm(const float* __restrict__ gates,
                                              float* __restrict__ h,
                                              float* __restrict__ c) {
    int idx = blockIdx.x * 256 + threadIdx.x;  // 0..32767
    int b = idx >> 9, d = idx & 511;
    const float* gb = gates + (size_t)b * Gn;
    float gi = gb[d], gf = gb[DECn + d], gg = gb[2 * DECn + d], go = gb[3 * DECn + d];
    float si = 1.f / (1.f + expf(-gi));
    float sf = 1.f / (1.f + expf(-gf));
    float so = 1.f / (1.f + expf(-go));
    float cc = sf * c[idx] + si * tanhf(gg);
    float hh = so * tanhf(cc);
    c[idx] = cc;
    h[idx] = hh;
}

// logits (-> d_out) and next-step hdec in one kernel.
// grid (120, 4): n in [0,30512), 16 b/thread
__global__ __launch_bounds__(256) void k_logits_hdec(const float* __restrict__ h,
                                                     const float* __restrict__ W_out,
                                                     const float* __restrict__ b_out,
                                                     const float* __restrict__ W_dec,
                                                     const float* __restrict__ b_dec,
                                                     float* __restrict__ out,
                                                     float* __restrict__ hdec, int t) {
    int n = blockIdx.x * 256 + threadIdx.x;
    int b0 = blockIdx.y * 16;
    bool isdec = (n >= Vn);
    int nn = isdec ? (n - Vn) : n;
    if (isdec && nn >= DECn) return;
    float bv = isdec ? b_dec[nn] : b_out[nn];
    float acc[16];
    #pragma unroll
    for (int j = 0; j < 16; ++j) acc[j] = bv;
    const float* Bp = isdec ? (W_dec + nn) : (W_out + nn);
    size_t strd = isdec ? (size_t)DECn : (size_t)Vn;
    for (int k = 0; k < DECn; ++k) {
        float w = *Bp; Bp += strd;
        #pragma unroll
        for (int j = 0; j < 16; ++j) acc[j] += h[(size_t)(b0 + j) * DECn + k] * w;
    }
    if (isdec) {
        #pragma unroll
        for (int j = 0; j < 16; ++j) hdec[(size_t)(b0 + j) * DECn + nn] = acc[j];
    } else {
        #pragma unroll
        for (int j = 0; j < 16; ++j)
            out[((size_t)(b0 + j) * STEPSn + t) * (size_t)Vn + nn] = acc[j];
    }
}

// ================= launcher =================

extern "C" void kernel_launch(void* const* d_in, const int* in_sizes, int n_in,
                              void* d_out, int out_size, void* d_ws, size_t ws_size,
                              hipStream_t stream) {
    const float* features    = (const float*)d_in[0];
    const int*   captions    = (const int*)d_in[1];
    const int*   caption_len = (const int*)d_in[2];
    const float* emb         = (const float*)d_in[3];
    const float* W_enc       = (const float*)d_in[4];
    const float* b_enc       = (const float*)d_in[5];
    const float* W_dec       = (const float*)d_in[6];
    const float* b_dec       = (const float*)d_in[7];
    const float* W_att       = (const float*)d_in[8];
    const float* b_att       = (const float*)d_in[9];
    const float* W_h0        = (const float*)d_in[10];
    const float* b_h0        = (const float*)d_in[11];
    const float* W_c0        = (const float*)d_in[12];
    const float* b_c0        = (const float*)d_in[13];
    const float* W_ih        = (const float*)d_in[14];
    const float* b_ih        = (const float*)d_in[15];
    const float* W_hh        = (const float*)d_in[16];
    const float* b_hh        = (const float*)d_in[17];
    const float* W_out       = (const float*)d_in[18];
    const float* b_out       = (const float*)d_in[19];

    float* out = (float*)d_out;
    float* ws  = (float*)d_ws;

    float* ws_encproj = ws + WS_ENCPROJ;
    float* ws_WihT    = ws + WS_WIHT;
    float* ws_WhhT    = ws + WS_WHHT;
    float* ws_meanf   = ws + WS_MEANF;
    float* ws_h       = ws + WS_H;
    float* ws_c       = ws + WS_C;
    float* ws_hdec    = ws + WS_HDEC;
    float* ws_ctx     = ws + WS_CTX;
    float* ws_gates   = ws + WS_GATES;

    // ---- precompute ----
    k_encproj<<<dim3(Pn * Bn / 64, ATTn / 64), 256, 0, stream>>>(features, W_enc, b_enc, ws_encproj);
    k_mean<<<dim3(Bn), 256, 0, stream>>>(features, ws_meanf);
    k_transpose<<<dim3((En + ENCn + 31) / 32, Gn / 32), 256, 0, stream>>>(W_ih, ws_WihT, Gn, En + ENCn);
    k_transpose<<<dim3(DECn / 32, Gn / 32), 256, 0, stream>>>(W_hh, ws_WhhT, Gn, DECn);
    k_init_state<<<dim3(2, 16), 256, 0, stream>>>(ws_meanf, W_h0, b_h0, W_c0, b_c0, ws_h, ws_c);
    k_small_gemm<<<dim3(2, 16), 256, 0, stream>>>(ws_h, DECn, W_dec, DECn, b_dec, ws_hdec);
    k_tail<<<dim3((Bn * Tn + Bn + 255) / 256), 256, 0, stream>>>(captions, caption_len, out);

    // ---- recurrence ----
    for (int t = 0; t < STEPSn; ++t) {
        k_attn<<<dim3(Bn), 256, 0, stream>>>(ws_encproj, ws_hdec, W_att, b_att,
                                             out + OUT_ALPHAS, t);
        k_ctx<<<dim3(Bn, ENCn / 256), 256, 0, stream>>>(features, out + OUT_ALPHAS, ws_ctx, t);
        k_gates<<<dim3(Gn / 256, 16), 256, 0, stream>>>(emb, captions, ws_ctx, ws_h,
                                                        ws_WihT, ws_WhhT, b_ih, b_hh,
                                                        ws_gates, t);
        k_lstm<<<dim3(Bn * DECn / 256), 256, 0, stream>>>(ws_gates, ws_h, ws_c);
        k_logits_hdec<<<dim3((Vn + DECn + 255) / 256, Bn / 16), 256, 0, stream>>>(
            ws_h, W_out, b_out, W_dec, b_dec, out, ws_hdec, t);
    }
}